// Round 6
// baseline (268.476 us; speedup 1.0000x reference)
//
#include <hip/hip_runtime.h>
#include <hip/hip_bf16.h>

#define DMODEL 1024
#define NH 16
#define HD 64
#define SEQ 2048
#define BATCH 2
#define BH (BATCH * NH)     // 32
#define MTOT (BATCH * SEQ)  // 4096

typedef _Float16 f16x8 __attribute__((ext_vector_type(8)));
typedef _Float16 f16x4 __attribute__((ext_vector_type(4)));
typedef _Float16 f16x2 __attribute__((ext_vector_type(2)));
typedef float f32x4 __attribute__((ext_vector_type(4)));
typedef float f32x16 __attribute__((ext_vector_type(16)));

__device__ __forceinline__ void gload_lds16(const void* g, void* l) {
  __builtin_amdgcn_global_load_lds((const __attribute__((address_space(1))) unsigned*)g,
                                   (__attribute__((address_space(3))) unsigned*)l, 16, 0, 0);
}

// ---------------------------------------------------------------------------
// K0a: fp32 -> fp16 flat convert (x)
// ---------------------------------------------------------------------------
__global__ __launch_bounds__(256) void cvt_f2h(const float* __restrict__ in,
                                               _Float16* __restrict__ out, int n8) {
  const int i = blockIdx.x * 256 + threadIdx.x;
  if (i < n8) {
    const float4 a = ((const float4*)in)[i * 2];
    const float4 b = ((const float4*)in)[i * 2 + 1];
    f16x8 o = {(_Float16)a.x, (_Float16)a.y, (_Float16)a.z, (_Float16)a.w,
               (_Float16)b.x, (_Float16)b.y, (_Float16)b.z, (_Float16)b.w};
    *(f16x8*)&out[(size_t)i * 8] = o;
  }
}

// ---------------------------------------------------------------------------
// K0b: fp32 [K][N] -> fp16 transposed [N][K]
// ---------------------------------------------------------------------------
__global__ __launch_bounds__(256) void cvt_transpose(const float* __restrict__ W,
                                                     _Float16* __restrict__ Wt,
                                                     int N, int K) {
  __shared__ float Ls[64][65];
  const int k0 = blockIdx.y * 64, n0 = blockIdx.x * 64;
  const int t = threadIdx.x;
  const int r = t >> 2, c4 = (t & 3) * 16;
#pragma unroll
  for (int j = 0; j < 4; ++j) {
    const float4 v = *(const float4*)&W[(size_t)(k0 + r) * N + n0 + c4 + j * 4];
    Ls[r][c4 + j * 4 + 0] = v.x;
    Ls[r][c4 + j * 4 + 1] = v.y;
    Ls[r][c4 + j * 4 + 2] = v.z;
    Ls[r][c4 + j * 4 + 3] = v.w;
  }
  __syncthreads();
  f16x8 o0, o1;
#pragma unroll
  for (int j = 0; j < 8; ++j) {
    o0[j] = (_Float16)Ls[c4 + j][r];
    o1[j] = (_Float16)Ls[c4 + 8 + j][r];
  }
  *(f16x8*)&Wt[(size_t)(n0 + r) * K + k0 + c4] = o0;
  *(f16x8*)&Wt[(size_t)(n0 + r) * K + k0 + c4 + 8] = o1;
}

// ---------------------------------------------------------------------------
// K1: QKV projection, fp16 MFMA (m97 structure, 128x128 tile, BK=64).
// Q pre-scaled by 0.125*log2(e) (softmax runs in exp2 domain).
// ---------------------------------------------------------------------------
__global__ __launch_bounds__(256) void qkv_mm(const _Float16* __restrict__ A,
                                              const _Float16* __restrict__ Bt,
                                              const float* __restrict__ bias,
                                              _Float16* __restrict__ qh,
                                              _Float16* __restrict__ kh,
                                              _Float16* __restrict__ vh) {
  __shared__ __align__(16) _Float16 As[128 * 64];
  __shared__ __align__(16) _Float16 Bs[128 * 64];
  const int t = threadIdx.x;
  const int w = t >> 6, lane = t & 63;
  const int g = lane >> 4, lr = lane & 15;
  const int m0 = blockIdx.y * 128, n0 = blockIdx.x * 128;
  const int wr = w >> 1, wc = w & 1;
  const int srow = (lane >> 3);
  const int col8 = (lane & 7) * 8;
  f32x4 acc[4][4] = {};

  for (int k0 = 0; k0 < DMODEL; k0 += 64) {
    __syncthreads();
#pragma unroll
    for (int i = 0; i < 4; ++i) {
      const int row = w * 32 + i * 8 + srow;
      gload_lds16(A + (size_t)(m0 + row) * DMODEL + k0 + col8, &As[(w * 4 + i) * 512]);
      gload_lds16(Bt + (size_t)(n0 + row) * DMODEL + k0 + col8, &Bs[(w * 4 + i) * 512]);
    }
    __syncthreads();
#pragma unroll
    for (int ks = 0; ks < 2; ++ks) {
      f16x8 af[4], bf[4];
#pragma unroll
      for (int mi = 0; mi < 4; ++mi)
        af[mi] = *(const f16x8*)&As[(wr * 64 + mi * 16 + lr) * 64 + ks * 32 + g * 8];
#pragma unroll
      for (int ni = 0; ni < 4; ++ni)
        bf[ni] = *(const f16x8*)&Bs[(wc * 64 + ni * 16 + lr) * 64 + ks * 32 + g * 8];
#pragma unroll
      for (int mi = 0; mi < 4; ++mi)
#pragma unroll
        for (int ni = 0; ni < 4; ++ni)
          acc[mi][ni] = __builtin_amdgcn_mfma_f32_16x16x32_f16(af[mi], bf[ni], acc[mi][ni], 0, 0, 0);
    }
  }

#pragma unroll
  for (int ni = 0; ni < 4; ++ni) {
    const int n = n0 + wc * 64 + ni * 16 + lr;
    const float bn = bias[n];
    const int which = n >> 10, d = n & 1023, h = d >> 6, hd = d & 63;
    _Float16* dst = which == 0 ? qh : which == 1 ? kh : vh;
    const float scale = which == 0 ? 0.18033688011f : 1.0f;  // 0.125*log2(e)
#pragma unroll
    for (int mi = 0; mi < 4; ++mi)
#pragma unroll
      for (int r = 0; r < 4; ++r) {
        const int m = m0 + wr * 64 + mi * 16 + g * 4 + r;
        const int bb = m >> 11, ss = m & 2047;
        dst[((size_t)(bb * NH + h) * SEQ + ss) * HD + hd] =
            (_Float16)((acc[mi][ni][r] + bn) * scale);
      }
  }
}

// ---------------------------------------------------------------------------
// K2 helpers
// ---------------------------------------------------------------------------
__device__ __forceinline__ void load_k(const _Float16* Kp, int kv0, int q, int hi,
                                       f16x8 (&kr)[8]) {
#pragma unroll
  for (int ks = 0; ks < 4; ++ks) {
    kr[2 * ks] = *(const f16x8*)(Kp + (size_t)(kv0 + q) * HD + ks * 16 + hi * 8);
    kr[2 * ks + 1] = *(const f16x8*)(Kp + (size_t)(kv0 + 32 + q) * HD + ks * 16 + hi * 8);
  }
}

__device__ __forceinline__ void load_v(const _Float16* Vp, int kv0, int skv, int sq4,
                                       f16x8 (&vr)[2]) {
  vr[0] = *(const f16x8*)(Vp + (size_t)(kv0 + skv) * HD + sq4 * 16);
  vr[1] = *(const f16x8*)(Vp + (size_t)(kv0 + skv) * HD + sq4 * 16 + 8);
}

__device__ __forceinline__ void store_v(_Float16 (*Vt)[76], int skv, int sq4,
                                        const f16x8 (&vr)[2]) {
#pragma unroll
  for (int e = 0; e < 8; ++e) {
    Vt[sq4 * 16 + e][skv] = vr[0][e];
    Vt[sq4 * 16 + 8 + e][skv] = vr[1][e];
  }
}

__device__ __forceinline__ void qkt(const f16x8 (&kr)[8], const f16x8 (&qf)[4],
                                    f32x16& s0, f32x16& s1) {
  s0 = {};
  s1 = {};
  __builtin_amdgcn_s_setprio(1);
#pragma unroll
  for (int ks = 0; ks < 4; ++ks) {
    s0 = __builtin_amdgcn_mfma_f32_32x32x16_f16(kr[2 * ks], qf[ks], s0, 0, 0, 0);
    s1 = __builtin_amdgcn_mfma_f32_32x32x16_f16(kr[2 * ks + 1], qf[ks], s1, 0, 0, 0);
  }
  __builtin_amdgcn_s_setprio(0);
}

// online softmax in exp2 domain with defer-max (THR=8 log2 units -> P <= 256)
__device__ __forceinline__ void softmax_update(f32x16& s0, f32x16& s1, float& mrun,
                                               float& lrun, f32x16& o0, f32x16& o1) {
  float tm[16];
#pragma unroll
  for (int r = 0; r < 16; ++r) tm[r] = fmaxf(s0[r], s1[r]);
#pragma unroll
  for (int d = 8; d > 0; d >>= 1)
#pragma unroll
    for (int r = 0; r < d; ++r) tm[r] = fmaxf(tm[r], tm[r + d]);
  const float mx = fmaxf(tm[0], __shfl_xor(tm[0], 32));
  if (!__all(mx <= mrun + 8.0f)) {
    const float mnew = fmaxf(mrun, mx);
    const float corr = exp2f(mrun - mnew);
    mrun = mnew;
    lrun *= corr;
#pragma unroll
    for (int r = 0; r < 16; ++r) {
      o0[r] *= corr;
      o1[r] *= corr;
    }
  }
#pragma unroll
  for (int r = 0; r < 16; ++r) {
    s0[r] = exp2f(s0[r] - mrun);
    s1[r] = exp2f(s1[r] - mrun);
  }
  float ts[16];
#pragma unroll
  for (int r = 0; r < 16; ++r) ts[r] = s0[r] + s1[r];
#pragma unroll
  for (int d = 8; d > 0; d >>= 1)
#pragma unroll
    for (int r = 0; r < d; ++r) ts[r] += ts[r + d];
  lrun += ts[0] + __shfl_xor(ts[0], 32);
}

// PV: O^T += V^T . P^T, building P^T B-frags in-register (verified r4/r5 mapping)
__device__ __forceinline__ void pv(const f32x16& s0, const f32x16& s1,
                                   const _Float16 (*Vt)[76], int q, int hi,
                                   f32x16& o0, f32x16& o1) {
#pragma unroll
  for (int ks = 0; ks < 4; ++ks) {
    const int base = 8 * (ks & 1);
    unsigned u0, u1, u2, u3;
#pragma unroll
    for (int w01 = 0; w01 < 2; ++w01) {
      float a0, a1, b0, b1;
      if (ks < 2) {
        a0 = s0[base + 2 * w01];     a1 = s0[base + 2 * w01 + 1];
        b0 = s0[base + 4 + 2 * w01]; b1 = s0[base + 4 + 2 * w01 + 1];
      } else {
        a0 = s1[base + 2 * w01];     a1 = s1[base + 2 * w01 + 1];
        b0 = s1[base + 4 + 2 * w01]; b1 = s1[base + 4 + 2 * w01 + 1];
      }
      f16x2 hm0; hm0[0] = (_Float16)a0; hm0[1] = (_Float16)a1;
      f16x2 hm1; hm1[0] = (_Float16)b0; hm1[1] = (_Float16)b1;
      unsigned Pm0, Pm1;
      __builtin_memcpy(&Pm0, &hm0, 4);
      __builtin_memcpy(&Pm1, &hm1, 4);
      const unsigned local = hi ? Pm1 : Pm0;
      const unsigned sent = hi ? Pm0 : Pm1;
      const unsigned cross = __shfl_xor(sent, 32);
      const unsigned wa = hi ? cross : local;
      const unsigned wb = hi ? local : cross;
      if (w01 == 0) { u0 = wa; u2 = wb; } else { u1 = wa; u3 = wb; }
    }
    unsigned ww[4] = {u0, u1, u2, u3};
    f16x8 pb;
    __builtin_memcpy(&pb, ww, 16);
    const f16x8 va0 = *(const f16x8*)&Vt[0 + q][ks * 16 + hi * 8];
    const f16x8 va1 = *(const f16x8*)&Vt[32 + q][ks * 16 + hi * 8];
    __builtin_amdgcn_s_setprio(1);
    o0 = __builtin_amdgcn_mfma_f32_32x32x16_f16(va0, pb, o0, 0, 0, 0);
    o1 = __builtin_amdgcn_mfma_f32_32x32x16_f16(va1, pb, o1, 0, 0, 0);
    __builtin_amdgcn_s_setprio(0);
  }
}

// ---------------------------------------------------------------------------
// K2: fused flash attention, swapped-QK^T 32x32, software-pipelined:
// double-buffered Vt, K/V prefetched one tile ahead, ONE barrier per tile.
// grid = (SEQ/128, BH), 256 thr = 4 waves x 32 q-rows. KVBLK = 64, NT = 32.
// ---------------------------------------------------------------------------
__global__ __launch_bounds__(256, 2) void attn_fused(const _Float16* __restrict__ qh,
                                                     const _Float16* __restrict__ kh,
                                                     const _Float16* __restrict__ vh,
                                                     _Float16* __restrict__ ao) {
  __shared__ __align__(16) _Float16 Vt[2][64][76];
  const int t = threadIdx.x;
  const int lane = t & 63, w = t >> 6;
  const int q = lane & 31, hi = lane >> 5;
  const int bh = blockIdx.y;
  const int q0 = blockIdx.x * 128 + w * 32;
  const _Float16* Qp = qh + (size_t)bh * SEQ * HD;
  const _Float16* Kp = kh + (size_t)bh * SEQ * HD;
  const _Float16* Vp = vh + (size_t)bh * SEQ * HD;

  f16x8 qf[4];
#pragma unroll
  for (int ks = 0; ks < 4; ++ks)
    qf[ks] = *(const f16x8*)(Qp + (size_t)(q0 + q) * HD + ks * 16 + hi * 8);

  const int skv = t & 63;
  const int sq4 = t >> 6;

  f16x8 kA[8], kB[8], vA[2], vB[2];
  load_v(Vp, 0, skv, sq4, vA);
  load_k(Kp, 0, q, hi, kA);
  store_v(Vt[0], skv, sq4, vA);

  f32x16 o0 = {}, o1 = {};
  float mrun = -3e30f, lrun = 0.f;
  f32x16 s0, s1;

#pragma unroll 1
  for (int t2 = 0; t2 < 16; ++t2) {
    const int kvE = t2 * 128;
    // ---- even tile (V in Vt[0]) ----
    qkt(kA, qf, s0, s1);
    load_v(Vp, kvE + 64, skv, sq4, vB);   // prefetch tile 2t2+1
    load_k(Kp, kvE + 64, q, hi, kB);
    softmax_update(s0, s1, mrun, lrun, o0, o1);
    __syncthreads();                      // PV(prev odd) done; Vt[0] writes visible
    store_v(Vt[1], skv, sq4, vB);
    pv(s0, s1, Vt[0], q, hi, o0, o1);
    // ---- odd tile (V in Vt[1]) ----
    qkt(kB, qf, s0, s1);
    if (t2 < 15) {
      load_v(Vp, kvE + 128, skv, sq4, vA);  // prefetch tile 2t2+2
      load_k(Kp, kvE + 128, q, hi, kA);
    }
    softmax_update(s0, s1, mrun, lrun, o0, o1);
    __syncthreads();                      // PV(even) done; Vt[1] writes visible
    if (t2 < 15) store_v(Vt[0], skv, sq4, vA);
    pv(s0, s1, Vt[1], q, hi, o0, o1);
  }

  const float invl = 1.0f / lrun;
  _Float16* aob = ao + (size_t)bh * SEQ * HD + (size_t)(q0 + q) * HD;
#pragma unroll
  for (int m = 0; m < 4; ++m) {
    f16x4 v0, v1;
#pragma unroll
    for (int s2 = 0; s2 < 4; ++s2) {
      v0[s2] = (_Float16)(o0[4 * m + s2] * invl);
      v1[s2] = (_Float16)(o1[4 * m + s2] * invl);
    }
    *(f16x4*)(aob + 8 * m + 4 * hi) = v0;
    *(f16x4*)(aob + 32 + 8 * m + 4 * hi) = v1;
  }
}

// ---------------------------------------------------------------------------
// K3: output projection, fp16 MFMA.
// ---------------------------------------------------------------------------
__global__ __launch_bounds__(256) void out_mm(const _Float16* __restrict__ Ah,
                                              const _Float16* __restrict__ Bt,
                                              const float* __restrict__ bias,
                                              float* __restrict__ out) {
  __shared__ __align__(16) _Float16 As[128 * 64];
  __shared__ __align__(16) _Float16 Bs[128 * 64];
  const int t = threadIdx.x;
  const int w = t >> 6, lane = t & 63;
  const int g = lane >> 4, lr = lane & 15;
  const int m0 = blockIdx.y * 128, n0 = blockIdx.x * 128;
  const int wr = w >> 1, wc = w & 1;
  const int srow = (lane >> 3);
  const int col8 = (lane & 7) * 8;
  f32x4 acc[4][4] = {};

  for (int k0 = 0; k0 < DMODEL; k0 += 64) {
    const int h = k0 >> 6;
    __syncthreads();
#pragma unroll
    for (int i = 0; i < 4; ++i) {
      const int row = w * 32 + i * 8 + srow;
      const int m = m0 + row;
      const int bb = m >> 11, ss = m & 2047;
      gload_lds16(Ah + ((size_t)(bb * NH + h) * SEQ + ss) * HD + col8, &As[(w * 4 + i) * 512]);
      gload_lds16(Bt + (size_t)(n0 + row) * DMODEL + k0 + col8, &Bs[(w * 4 + i) * 512]);
    }
    __syncthreads();
#pragma unroll
    for (int ks = 0; ks < 2; ++ks) {
      f16x8 af[4], bf[4];
#pragma unroll
      for (int mi = 0; mi < 4; ++mi)
        af[mi] = *(const f16x8*)&As[(wr * 64 + mi * 16 + lr) * 64 + ks * 32 + g * 8];
#pragma unroll
      for (int ni = 0; ni < 4; ++ni)
        bf[ni] = *(const f16x8*)&Bs[(wc * 64 + ni * 16 + lr) * 64 + ks * 32 + g * 8];
#pragma unroll
      for (int mi = 0; mi < 4; ++mi)
#pragma unroll
        for (int ni = 0; ni < 4; ++ni)
          acc[mi][ni] = __builtin_amdgcn_mfma_f32_16x16x32_f16(af[mi], bf[ni], acc[mi][ni], 0, 0, 0);
    }
  }

#pragma unroll
  for (int ni = 0; ni < 4; ++ni) {
    const int n = n0 + wc * 64 + ni * 16 + lr;
    const float bn = bias[n];
#pragma unroll
    for (int mi = 0; mi < 4; ++mi)
#pragma unroll
      for (int r = 0; r < 4; ++r) {
        const int m = m0 + wr * 64 + mi * 16 + g * 4 + r;
        out[(size_t)m * DMODEL + n] = acc[mi][ni][r] + bn;
      }
  }
}

// ---------------------------------------------------------------------------
extern "C" void kernel_launch(void* const* d_in, const int* in_sizes, int n_in,
                              void* d_out, int out_size, void* d_ws, size_t ws_size,
                              hipStream_t stream) {
  const float* x = (const float*)d_in[0];
  const float* Wqkv = (const float*)d_in[1];
  const float* bqkv = (const float*)d_in[2];
  const float* Wout = (const float*)d_in[3];
  const float* bout = (const float*)d_in[4];
  float* out = (float*)d_out;

  char* ws = (char*)d_ws;
  const size_t MB = 1u << 20;
  _Float16* Xh = (_Float16*)(ws);                          // 8 MiB
  _Float16* qh = (_Float16*)(ws + 8 * MB);                 // 8 MiB
  _Float16* kh = (_Float16*)(ws + 16 * MB);                // 8 MiB
  _Float16* vh = (_Float16*)(ws + 24 * MB);                // 8 MiB
  _Float16* Wtq = (_Float16*)(ws + 32 * MB);               // 6 MiB
  _Float16* Wto = (_Float16*)(ws + 38 * MB + 512 * 1024);  // 2 MiB
  _Float16* attnh = Xh;                                    // reuse after qkv_mm

  cvt_f2h<<<dim3(MTOT * DMODEL / 8 / 256), 256, 0, stream>>>(x, Xh, MTOT * DMODEL / 8);
  cvt_transpose<<<dim3(3072 / 64, DMODEL / 64), 256, 0, stream>>>(Wqkv, Wtq, 3072, DMODEL);
  cvt_transpose<<<dim3(DMODEL / 64, DMODEL / 64), 256, 0, stream>>>(Wout, Wto, DMODEL, DMODEL);
  qkv_mm<<<dim3(3072 / 128, MTOT / 128), 256, 0, stream>>>(Xh, Wtq, bqkv, qh, kh, vh);
  attn_fused<<<dim3(SEQ / 128, BH), 256, 0, stream>>>(qh, kh, vh, attnh);
  out_mm<<<dim3(DMODEL / 128, MTOT / 128), 256, 0, stream>>>(attnh, Wto, bout, out);
}

// Round 7
// 259.519 us; speedup vs baseline: 1.0345x; 1.0345x over previous
//
#include <hip/hip_runtime.h>
#include <hip/hip_bf16.h>

#define DMODEL 1024
#define NH 16
#define HD 64
#define SEQ 2048
#define BATCH 2
#define BH (BATCH * NH)     // 32
#define MTOT (BATCH * SEQ)  // 4096

typedef _Float16 f16x8 __attribute__((ext_vector_type(8)));
typedef _Float16 f16x4 __attribute__((ext_vector_type(4)));
typedef _Float16 f16x2 __attribute__((ext_vector_type(2)));
typedef float f32x4 __attribute__((ext_vector_type(4)));
typedef float f32x16 __attribute__((ext_vector_type(16)));

__device__ __forceinline__ void gload_lds16(const void* g, void* l) {
  __builtin_amdgcn_global_load_lds((const __attribute__((address_space(1))) unsigned*)g,
                                   (__attribute__((address_space(3))) unsigned*)l, 16, 0, 0);
}

// ---------------------------------------------------------------------------
// K0a: fp32 -> fp16 flat convert (x)
// ---------------------------------------------------------------------------
__global__ __launch_bounds__(256) void cvt_f2h(const float* __restrict__ in,
                                               _Float16* __restrict__ out, int n8) {
  const int i = blockIdx.x * 256 + threadIdx.x;
  if (i < n8) {
    const float4 a = ((const float4*)in)[i * 2];
    const float4 b = ((const float4*)in)[i * 2 + 1];
    f16x8 o = {(_Float16)a.x, (_Float16)a.y, (_Float16)a.z, (_Float16)a.w,
               (_Float16)b.x, (_Float16)b.y, (_Float16)b.z, (_Float16)b.w};
    *(f16x8*)&out[(size_t)i * 8] = o;
  }
}

// ---------------------------------------------------------------------------
// K0b: fp32 [K][N] -> fp16 transposed [N][K]
// ---------------------------------------------------------------------------
__global__ __launch_bounds__(256) void cvt_transpose(const float* __restrict__ W,
                                                     _Float16* __restrict__ Wt,
                                                     int N, int K) {
  __shared__ float Ls[64][65];
  const int k0 = blockIdx.y * 64, n0 = blockIdx.x * 64;
  const int t = threadIdx.x;
  const int r = t >> 2, c4 = (t & 3) * 16;
#pragma unroll
  for (int j = 0; j < 4; ++j) {
    const float4 v = *(const float4*)&W[(size_t)(k0 + r) * N + n0 + c4 + j * 4];
    Ls[r][c4 + j * 4 + 0] = v.x;
    Ls[r][c4 + j * 4 + 1] = v.y;
    Ls[r][c4 + j * 4 + 2] = v.z;
    Ls[r][c4 + j * 4 + 3] = v.w;
  }
  __syncthreads();
  f16x8 o0, o1;
#pragma unroll
  for (int j = 0; j < 8; ++j) {
    o0[j] = (_Float16)Ls[c4 + j][r];
    o1[j] = (_Float16)Ls[c4 + 8 + j][r];
  }
  *(f16x8*)&Wt[(size_t)(n0 + r) * K + k0 + c4] = o0;
  *(f16x8*)&Wt[(size_t)(n0 + r) * K + k0 + c4 + 8] = o1;
}

// ---------------------------------------------------------------------------
// K1: QKV projection, fp16 MFMA (m97 structure, 128x128 tile, BK=64).
// Q pre-scaled by 0.125*log2(e) (softmax runs in exp2 domain).
// ---------------------------------------------------------------------------
__global__ __launch_bounds__(256) void qkv_mm(const _Float16* __restrict__ A,
                                              const _Float16* __restrict__ Bt,
                                              const float* __restrict__ bias,
                                              _Float16* __restrict__ qh,
                                              _Float16* __restrict__ kh,
                                              _Float16* __restrict__ vh) {
  __shared__ __align__(16) _Float16 As[128 * 64];
  __shared__ __align__(16) _Float16 Bs[128 * 64];
  const int t = threadIdx.x;
  const int w = t >> 6, lane = t & 63;
  const int g = lane >> 4, lr = lane & 15;
  const int m0 = blockIdx.y * 128, n0 = blockIdx.x * 128;
  const int wr = w >> 1, wc = w & 1;
  const int srow = (lane >> 3);
  const int col8 = (lane & 7) * 8;
  f32x4 acc[4][4] = {};

  for (int k0 = 0; k0 < DMODEL; k0 += 64) {
    __syncthreads();
#pragma unroll
    for (int i = 0; i < 4; ++i) {
      const int row = w * 32 + i * 8 + srow;
      gload_lds16(A + (size_t)(m0 + row) * DMODEL + k0 + col8, &As[(w * 4 + i) * 512]);
      gload_lds16(Bt + (size_t)(n0 + row) * DMODEL + k0 + col8, &Bs[(w * 4 + i) * 512]);
    }
    __syncthreads();
#pragma unroll
    for (int ks = 0; ks < 2; ++ks) {
      f16x8 af[4], bf[4];
#pragma unroll
      for (int mi = 0; mi < 4; ++mi)
        af[mi] = *(const f16x8*)&As[(wr * 64 + mi * 16 + lr) * 64 + ks * 32 + g * 8];
#pragma unroll
      for (int ni = 0; ni < 4; ++ni)
        bf[ni] = *(const f16x8*)&Bs[(wc * 64 + ni * 16 + lr) * 64 + ks * 32 + g * 8];
#pragma unroll
      for (int mi = 0; mi < 4; ++mi)
#pragma unroll
        for (int ni = 0; ni < 4; ++ni)
          acc[mi][ni] = __builtin_amdgcn_mfma_f32_16x16x32_f16(af[mi], bf[ni], acc[mi][ni], 0, 0, 0);
    }
  }

#pragma unroll
  for (int ni = 0; ni < 4; ++ni) {
    const int n = n0 + wc * 64 + ni * 16 + lr;
    const float bn = bias[n];
    const int which = n >> 10, d = n & 1023, h = d >> 6, hd = d & 63;
    _Float16* dst = which == 0 ? qh : which == 1 ? kh : vh;
    const float scale = which == 0 ? 0.18033688011f : 1.0f;  // 0.125*log2(e)
#pragma unroll
    for (int mi = 0; mi < 4; ++mi)
#pragma unroll
      for (int r = 0; r < 4; ++r) {
        const int m = m0 + wr * 64 + mi * 16 + g * 4 + r;
        const int bb = m >> 11, ss = m & 2047;
        dst[((size_t)(bb * NH + h) * SEQ + ss) * HD + hd] =
            (_Float16)((acc[mi][ni][r] + bn) * scale);
      }
  }
}

// ---------------------------------------------------------------------------
// K2: fused flash attention, swapped-QK^T 32x32 (r5 structure) + XCD swizzle.
// 1D grid of 512 blocks; decode so all 16 q-tiles of one head share an XCD:
//   bh = (wgid%8)*4 + (wgid>>3)%4 ; qt = wgid>>5  (bijective on [0,512))
// 256 thr = 4 waves x 32 q-rows; KVBLK = 64; each lane owns one q row.
// ---------------------------------------------------------------------------
__global__ __launch_bounds__(256, 2) void attn_fused(const _Float16* __restrict__ qh,
                                                     const _Float16* __restrict__ kh,
                                                     const _Float16* __restrict__ vh,
                                                     _Float16* __restrict__ ao) {
  __shared__ __align__(16) _Float16 Vt[64][76];  // V^T tile [d][kv]
  const int t = threadIdx.x;
  const int lane = t & 63, w = t >> 6;
  const int q = lane & 31, hi = lane >> 5;
  const int wgid = blockIdx.x;
  const int bh = (wgid & 7) * 4 + ((wgid >> 3) & 3);
  const int qt = wgid >> 5;
  const int q0 = qt * 128 + w * 32;
  const _Float16* Qp = qh + (size_t)bh * SEQ * HD;
  const _Float16* Kp = kh + (size_t)bh * SEQ * HD;
  const _Float16* Vp = vh + (size_t)bh * SEQ * HD;

  // Q as B-operand frags (pre-scaled by 0.125*log2e in qkv_mm)
  f16x8 qf[4];
#pragma unroll
  for (int ks = 0; ks < 4; ++ks)
    qf[ks] = *(const f16x8*)(Qp + (size_t)(q0 + q) * HD + ks * 16 + hi * 8);

  f32x16 o0 = {}, o1 = {};  // O^T accum: d = 32*db + (r&3) + 8*(r>>2) + 4*hi
  float mrun = -3e30f, lrun = 0.f;

  const int skv = t & 63;   // staging: kv row
  const int sq4 = t >> 6;   // staging: d quarter

  for (int kv0 = 0; kv0 < SEQ; kv0 += 64) {
    // ---- stage V^T into LDS (transpose on write) ----
    const f16x8 sv0 = *(const f16x8*)(Vp + (size_t)(kv0 + skv) * HD + sq4 * 16);
    const f16x8 sv1 = *(const f16x8*)(Vp + (size_t)(kv0 + skv) * HD + sq4 * 16 + 8);
    __syncthreads();  // previous tile's Vt reads complete
#pragma unroll
    for (int e = 0; e < 8; ++e) {
      Vt[sq4 * 16 + e][skv] = sv0[e];
      Vt[sq4 * 16 + 8 + e][skv] = sv1[e];
    }

    // ---- QK^T (swapped): S^T[kv][q] = K . Q^T ; K direct from global ----
    f32x16 s0 = {}, s1 = {};
    __builtin_amdgcn_s_setprio(1);
#pragma unroll
    for (int ks = 0; ks < 4; ++ks) {
      const f16x8 k0 = *(const f16x8*)(Kp + (size_t)(kv0 + q) * HD + ks * 16 + hi * 8);
      const f16x8 k1 = *(const f16x8*)(Kp + (size_t)(kv0 + 32 + q) * HD + ks * 16 + hi * 8);
      s0 = __builtin_amdgcn_mfma_f32_32x32x16_f16(k0, qf[ks], s0, 0, 0, 0);
      s1 = __builtin_amdgcn_mfma_f32_32x32x16_f16(k1, qf[ks], s1, 0, 0, 0);
    }
    __builtin_amdgcn_s_setprio(0);

    // ---- online softmax (exp2 domain, defer-max THR=8) ----
    float tm[16];
#pragma unroll
    for (int r = 0; r < 16; ++r) tm[r] = fmaxf(s0[r], s1[r]);
#pragma unroll
    for (int d = 8; d > 0; d >>= 1)
#pragma unroll
      for (int r = 0; r < d; ++r) tm[r] = fmaxf(tm[r], tm[r + d]);
    const float mx = fmaxf(tm[0], __shfl_xor(tm[0], 32));
    if (!__all(mx <= mrun + 8.0f)) {
      const float mnew = fmaxf(mrun, mx);
      const float corr = exp2f(mrun - mnew);
      mrun = mnew;
      lrun *= corr;
#pragma unroll
      for (int r = 0; r < 16; ++r) {
        o0[r] *= corr;
        o1[r] *= corr;
      }
    }
#pragma unroll
    for (int r = 0; r < 16; ++r) {
      s0[r] = exp2f(s0[r] - mrun);
      s1[r] = exp2f(s1[r] - mrun);
    }
    float ts[16];
#pragma unroll
    for (int r = 0; r < 16; ++r) ts[r] = s0[r] + s1[r];
#pragma unroll
    for (int d = 8; d > 0; d >>= 1)
#pragma unroll
      for (int r = 0; r < d; ++r) ts[r] += ts[r + d];
    lrun += ts[0] + __shfl_xor(ts[0], 32);

    __syncthreads();  // Vt writes visible

    // ---- PV: O^T += V^T . P^T. Build P^T B-frags in-register. ----
#pragma unroll
    for (int ks = 0; ks < 4; ++ks) {
      const int base = 8 * (ks & 1);
      unsigned u0, u1, u2, u3;
#pragma unroll
      for (int w01 = 0; w01 < 2; ++w01) {
        float a0, a1, b0, b1;
        if (ks < 2) {
          a0 = s0[base + 2 * w01];     a1 = s0[base + 2 * w01 + 1];
          b0 = s0[base + 4 + 2 * w01]; b1 = s0[base + 4 + 2 * w01 + 1];
        } else {
          a0 = s1[base + 2 * w01];     a1 = s1[base + 2 * w01 + 1];
          b0 = s1[base + 4 + 2 * w01]; b1 = s1[base + 4 + 2 * w01 + 1];
        }
        f16x2 hm0; hm0[0] = (_Float16)a0; hm0[1] = (_Float16)a1;
        f16x2 hm1; hm1[0] = (_Float16)b0; hm1[1] = (_Float16)b1;
        unsigned Pm0, Pm1;
        __builtin_memcpy(&Pm0, &hm0, 4);
        __builtin_memcpy(&Pm1, &hm1, 4);
        const unsigned local = hi ? Pm1 : Pm0;
        const unsigned sent = hi ? Pm0 : Pm1;
        const unsigned cross = __shfl_xor(sent, 32);
        const unsigned wa = hi ? cross : local;
        const unsigned wb = hi ? local : cross;
        if (w01 == 0) { u0 = wa; u2 = wb; } else { u1 = wa; u3 = wb; }
      }
      unsigned ww[4] = {u0, u1, u2, u3};
      f16x8 pb;
      __builtin_memcpy(&pb, ww, 16);
      const f16x8 va0 = *(const f16x8*)&Vt[0 + q][ks * 16 + hi * 8];
      const f16x8 va1 = *(const f16x8*)&Vt[32 + q][ks * 16 + hi * 8];
      __builtin_amdgcn_s_setprio(1);
      o0 = __builtin_amdgcn_mfma_f32_32x32x16_f16(va0, pb, o0, 0, 0, 0);
      o1 = __builtin_amdgcn_mfma_f32_32x32x16_f16(va1, pb, o1, 0, 0, 0);
      __builtin_amdgcn_s_setprio(0);
    }
  }

  // ---- epilogue ----
  const float invl = 1.0f / lrun;
  _Float16* aob = ao + (size_t)bh * SEQ * HD + (size_t)(q0 + q) * HD;
#pragma unroll
  for (int m = 0; m < 4; ++m) {
    f16x4 v0, v1;
#pragma unroll
    for (int s2 = 0; s2 < 4; ++s2) {
      v0[s2] = (_Float16)(o0[4 * m + s2] * invl);
      v1[s2] = (_Float16)(o1[4 * m + s2] * invl);
    }
    *(f16x4*)(aob + 8 * m + 4 * hi) = v0;
    *(f16x4*)(aob + 32 + 8 * m + 4 * hi) = v1;
  }
}

// ---------------------------------------------------------------------------
// K3: output projection, fp16 MFMA.
// ---------------------------------------------------------------------------
__global__ __launch_bounds__(256) void out_mm(const _Float16* __restrict__ Ah,
                                              const _Float16* __restrict__ Bt,
                                              const float* __restrict__ bias,
                                              float* __restrict__ out) {
  __shared__ __align__(16) _Float16 As[128 * 64];
  __shared__ __align__(16) _Float16 Bs[128 * 64];
  const int t = threadIdx.x;
  const int w = t >> 6, lane = t & 63;
  const int g = lane >> 4, lr = lane & 15;
  const int m0 = blockIdx.y * 128, n0 = blockIdx.x * 128;
  const int wr = w >> 1, wc = w & 1;
  const int srow = (lane >> 3);
  const int col8 = (lane & 7) * 8;
  f32x4 acc[4][4] = {};

  for (int k0 = 0; k0 < DMODEL; k0 += 64) {
    const int h = k0 >> 6;
    __syncthreads();
#pragma unroll
    for (int i = 0; i < 4; ++i) {
      const int row = w * 32 + i * 8 + srow;
      const int m = m0 + row;
      const int bb = m >> 11, ss = m & 2047;
      gload_lds16(Ah + ((size_t)(bb * NH + h) * SEQ + ss) * HD + col8, &As[(w * 4 + i) * 512]);
      gload_lds16(Bt + (size_t)(n0 + row) * DMODEL + k0 + col8, &Bs[(w * 4 + i) * 512]);
    }
    __syncthreads();
#pragma unroll
    for (int ks = 0; ks < 2; ++ks) {
      f16x8 af[4], bf[4];
#pragma unroll
      for (int mi = 0; mi < 4; ++mi)
        af[mi] = *(const f16x8*)&As[(wr * 64 + mi * 16 + lr) * 64 + ks * 32 + g * 8];
#pragma unroll
      for (int ni = 0; ni < 4; ++ni)
        bf[ni] = *(const f16x8*)&Bs[(wc * 64 + ni * 16 + lr) * 64 + ks * 32 + g * 8];
#pragma unroll
      for (int mi = 0; mi < 4; ++mi)
#pragma unroll
        for (int ni = 0; ni < 4; ++ni)
          acc[mi][ni] = __builtin_amdgcn_mfma_f32_16x16x32_f16(af[mi], bf[ni], acc[mi][ni], 0, 0, 0);
    }
  }

#pragma unroll
  for (int ni = 0; ni < 4; ++ni) {
    const int n = n0 + wc * 64 + ni * 16 + lr;
    const float bn = bias[n];
#pragma unroll
    for (int mi = 0; mi < 4; ++mi)
#pragma unroll
      for (int r = 0; r < 4; ++r) {
        const int m = m0 + wr * 64 + mi * 16 + g * 4 + r;
        out[(size_t)m * DMODEL + n] = acc[mi][ni][r] + bn;
      }
  }
}

// ---------------------------------------------------------------------------
extern "C" void kernel_launch(void* const* d_in, const int* in_sizes, int n_in,
                              void* d_out, int out_size, void* d_ws, size_t ws_size,
                              hipStream_t stream) {
  const float* x = (const float*)d_in[0];
  const float* Wqkv = (const float*)d_in[1];
  const float* bqkv = (const float*)d_in[2];
  const float* Wout = (const float*)d_in[3];
  const float* bout = (const float*)d_in[4];
  float* out = (float*)d_out;

  char* ws = (char*)d_ws;
  const size_t MB = 1u << 20;
  _Float16* Xh = (_Float16*)(ws);                          // 8 MiB
  _Float16* qh = (_Float16*)(ws + 8 * MB);                 // 8 MiB
  _Float16* kh = (_Float16*)(ws + 16 * MB);                // 8 MiB
  _Float16* vh = (_Float16*)(ws + 24 * MB);                // 8 MiB
  _Float16* Wtq = (_Float16*)(ws + 32 * MB);               // 6 MiB
  _Float16* Wto = (_Float16*)(ws + 38 * MB + 512 * 1024);  // 2 MiB
  _Float16* attnh = Xh;                                    // reuse after qkv_mm

  cvt_f2h<<<dim3(MTOT * DMODEL / 8 / 256), 256, 0, stream>>>(x, Xh, MTOT * DMODEL / 8);
  cvt_transpose<<<dim3(3072 / 64, DMODEL / 64), 256, 0, stream>>>(Wqkv, Wtq, 3072, DMODEL);
  cvt_transpose<<<dim3(DMODEL / 64, DMODEL / 64), 256, 0, stream>>>(Wout, Wto, DMODEL, DMODEL);
  qkv_mm<<<dim3(3072 / 128, MTOT / 128), 256, 0, stream>>>(Xh, Wtq, bqkv, qh, kh, vh);
  attn_fused<<<dim3(512), 256, 0, stream>>>(qh, kh, vh, attnh);
  out_mm<<<dim3(DMODEL / 128, MTOT / 128), 256, 0, stream>>>(attnh, Wto, bout, out);
}